// Round 2
// baseline (496.151 us; speedup 1.0000x reference)
//
#include <hip/hip_runtime.h>

// Per-sample depthwise 7x7 cross-correlation, NHWC, SAME padding.
// inputs:  [B,H,W,C] fp32, kernels: [B,7,7,C] fp32, out: [B,H,W,C] fp32.
// out[b,y,x,c] = sum_{i,j} in[b, y+i-3, x+j-3, c] * ker[b,i,j,c]  (zero pad)

#define BB 32
#define HH 128
#define WW 128
#define CC 128
#define KH 7
#define KW 7

#define XPT 4                       // x outputs per thread
#define NTAP (XPT + KW - 1)         // 10 input columns per row per thread
#define YSPLIT 2
#define YROWS (HH / YSPLIT)         // 64
#define NXS (WW / (XPT * 2))        // 16 x-slabs (2 x-groups of 4 per block)
#define GRID (BB * NXS * YSPLIT)    // 1024 blocks

__global__ __launch_bounds__(256, 4) void crossconv_kernel(
    const float* __restrict__ in,
    const float* __restrict__ ker,
    float* __restrict__ out)
{
    const int tid = threadIdx.x;
    const int c  = tid & (CC - 1);   // lanes contiguous in c -> coalesced
    const int xg = tid >> 7;         // 0..1, wave-uniform

    // Bijective XCD swizzle (GRID % 8 == 0): each XCD gets a contiguous
    // 128-block chunk = 4 full samples (all x-slabs, both y-halves) -> halo
    // sharing stays in one XCD's L2.
    const int bid = blockIdx.x;
    const int swz = (bid & 7) * (GRID / 8) + (bid >> 3);
    const int b  = swz >> 5;         // 32 blocks per sample
    const int yh = (swz >> 4) & 1;
    const int xs = swz & 15;
    const int x0 = (xs * 2 + xg) * XPT;   // first output column, 0..124
    const int y0 = yh * YROWS;

    // Hoist all 49 weights for (b, :, :, c); asm pins them in VGPRs
    // (prevents the compiler from rematerializing the loads in the loop).
    float w[KH][KW];
    {
        const float* kb = ker + ((size_t)b * KH * KW) * CC + c;
        #pragma unroll
        for (int i = 0; i < KH; ++i)
            #pragma unroll
            for (int j = 0; j < KW; ++j) {
                w[i][j] = kb[(i * KW + j) * CC];
                asm("" : "+v"(w[i][j]));
            }
    }

    const float* ib = in  + ((size_t)b * HH * WW) * CC;
    float*       ob = out + ((size_t)b * HH * WW) * CC;

    // taps cover columns x0-3 .. x0+XPT+2 ; wave-uniform interior test
    const bool interior = (x0 >= 3) && (x0 + XPT + 2 < WW);

    auto load_row = [&](float* t, int yi) {
        if (yi < 0 || yi >= HH) {
            #pragma unroll
            for (int j = 0; j < NTAP; ++j) t[j] = 0.0f;
            return;
        }
        const float* row = ib + (size_t)yi * WW * CC + c;
        if (interior) {
            #pragma unroll
            for (int j = 0; j < NTAP; ++j)
                t[j] = row[(x0 - 3 + j) * CC];
        } else {
            #pragma unroll
            for (int j = 0; j < NTAP; ++j) {
                const int xx = x0 - 3 + j;
                t[j] = (xx >= 0 && xx < WW) ? row[xx * CC] : 0.0f;
            }
        }
    };

    // Sliding ring: acc[s][xo] is partial for output row y = yi-3+s.
    float acc[KH][XPT];
    #pragma unroll
    for (int s = 0; s < KH; ++s)
        #pragma unroll
        for (int xo = 0; xo < XPT; ++xo) acc[s][xo] = 0.0f;

    const int yi0 = y0 - 3;
    const int yi1 = y0 + YROWS + 2;   // last input row feeding y0+YROWS-1

    float t[NTAP], tn[NTAP];
    load_row(t, yi0);

    for (int yi = yi0; yi <= yi1; ++yi) {
        // Prefetch next row's taps; FMA burst below hides the latency.
        load_row(tn, (yi < yi1) ? (yi + 1) : -1);

        // Input row yi feeds output y = yi-3+s with kernel row i = 6-s.
        #pragma unroll
        for (int i = 0; i < KH; ++i)
            #pragma unroll
            for (int j = 0; j < KW; ++j)
                #pragma unroll
                for (int xo = 0; xo < XPT; ++xo)
                    acc[6 - i][xo] = fmaf(w[i][j], t[xo + j], acc[6 - i][xo]);

        const int y = yi - 3;
        if (y >= y0) {                       // upper bound guaranteed by loop end
            float* orow = ob + ((size_t)y * WW + x0) * CC + c;
            #pragma unroll
            for (int xo = 0; xo < XPT; ++xo)
                orow[xo * CC] = acc[0][xo];
        }

        // Shift ring, open fresh top slot.
        #pragma unroll
        for (int s = 0; s < KH - 1; ++s)
            #pragma unroll
            for (int xo = 0; xo < XPT; ++xo) acc[s][xo] = acc[s + 1][xo];
        #pragma unroll
        for (int xo = 0; xo < XPT; ++xo) acc[KH - 1][xo] = 0.0f;

        #pragma unroll
        for (int j = 0; j < NTAP; ++j) t[j] = tn[j];
    }
}

extern "C" void kernel_launch(void* const* d_in, const int* in_sizes, int n_in,
                              void* d_out, int out_size, void* d_ws, size_t ws_size,
                              hipStream_t stream) {
    const float* in  = (const float*)d_in[0];
    const float* ker = (const float*)d_in[1];
    float*       out = (float*)d_out;

    crossconv_kernel<<<GRID, 256, 0, stream>>>(in, ker, out);
}

// Round 3
// 335.777 us; speedup vs baseline: 1.4776x; 1.4776x over previous
//
#include <hip/hip_runtime.h>

// Per-sample depthwise 7x7 cross-correlation, NHWC, SAME padding.
// inputs:  [B,H,W,C] fp32, kernels: [B,7,7,C] fp32, out: [B,H,W,C] fp32.
// out[b,y,x,c] = sum_{i,j} in[b, y+i-3, x+j-3, c] * ker[b,i,j,c]  (zero pad)

#define BB 32
#define HH 128
#define WW 128
#define CC 128
#define KH 7
#define KW 7

#define XPT 4                        // x outputs per thread
#define NTAP (XPT + KW - 1)          // 10 input columns per row per thread
#define XG 8                         // x-groups per block (1024 threads / 128 c)
#define SLABW (XG * XPT)             // 32 output columns per block
#define NXS (WW / SLABW)             // 4 x-slabs
#define YSPLIT 2
#define YROWS (HH / YSPLIT)          // 64 output rows per block
#define GRID (BB * NXS * YSPLIT)     // 256 blocks = 1 per CU

__global__
__attribute__((amdgpu_flat_work_group_size(1024, 1024), amdgpu_waves_per_eu(4, 4)))
void crossconv_kernel(
    const float* __restrict__ in,
    const float* __restrict__ ker,
    float* __restrict__ out)
{
    const int tid = threadIdx.x;
    const int c  = tid & (CC - 1);   // lanes contiguous in c -> coalesced
    const int xg = tid >> 7;         // 0..7, wave-uniform (wave = 64 lanes)

    // Bijective XCD swizzle (GRID=256, 32 blocks per XCD): each XCD gets
    // 4 consecutive samples (8 blocks each: 4 x-slabs x 2 y-halves) so the
    // x/y halo sharing stays within one XCD's L2.
    const int bid = blockIdx.x;
    const int swz = (bid & 7) * (GRID / 8) + (bid >> 3);
    const int b  = swz >> 3;         // 8 blocks per sample
    const int xs = (swz >> 1) & 3;
    const int yh = swz & 1;
    const int x0 = xs * SLABW + xg * XPT;  // first output column for this thread
    const int y0 = yh * YROWS;

    // Hoist all 49 weights for (b, :, :, c); asm pins the loaded values so
    // the compiler cannot rematerialize the loads inside the row loop.
    float w[KH][KW];
    {
        const float* kb = ker + ((size_t)b * KH * KW) * CC + c;
        #pragma unroll
        for (int i = 0; i < KH; ++i)
            #pragma unroll
            for (int j = 0; j < KW; ++j) {
                w[i][j] = kb[(i * KW + j) * CC];
                asm("" : "+v"(w[i][j]));
            }
    }

    const float* ib = in  + ((size_t)b * HH * WW) * CC;
    float*       ob = out + ((size_t)b * HH * WW) * CC;

    // Taps cover columns x0-3 .. x0+XPT+2; wave-uniform edge test.
    const bool interior = (x0 >= 3) && (x0 + XPT + 2 < WW);

    // Sliding accumulator ring: acc[s][xo] is partial for output row y = yi-3+s.
    float acc[KH][XPT];
    #pragma unroll
    for (int s = 0; s < KH; ++s)
        #pragma unroll
        for (int xo = 0; xo < XPT; ++xo) acc[s][xo] = 0.0f;

    const int yi0 = y0 - 3;
    const int yi1 = y0 + YROWS + 2;  // last input row feeding y0+YROWS-1

    #pragma unroll 1
    for (int yi = yi0; yi <= yi1; ++yi) {
        // Load this row's taps.
        float t[NTAP];
        if (yi >= 0 && yi < HH) {
            const float* row = ib + (size_t)yi * WW * CC + c;
            if (interior) {
                #pragma unroll
                for (int j = 0; j < NTAP; ++j)
                    t[j] = row[(x0 - 3 + j) * CC];
            } else {
                #pragma unroll
                for (int j = 0; j < NTAP; ++j) {
                    const int xx = x0 - 3 + j;
                    t[j] = (xx >= 0 && xx < WW) ? row[xx * CC] : 0.0f;
                }
            }
        } else {
            #pragma unroll
            for (int j = 0; j < NTAP; ++j) t[j] = 0.0f;
        }

        // Input row yi feeds output y = yi-3+s with kernel row i = 6-s.
        #pragma unroll
        for (int i = 0; i < KH; ++i)
            #pragma unroll
            for (int j = 0; j < KW; ++j)
                #pragma unroll
                for (int xo = 0; xo < XPT; ++xo)
                    acc[6 - i][xo] = fmaf(w[i][j], t[xo + j], acc[6 - i][xo]);

        const int y = yi - 3;
        if (y >= y0) {                       // upper bound guaranteed by loop end
            float* orow = ob + ((size_t)y * WW + x0) * CC + c;
            #pragma unroll
            for (int xo = 0; xo < XPT; ++xo)
                orow[xo * CC] = acc[0][xo];
        }

        // Shift ring, open fresh top slot.
        #pragma unroll
        for (int s = 0; s < KH - 1; ++s)
            #pragma unroll
            for (int xo = 0; xo < XPT; ++xo) acc[s][xo] = acc[s + 1][xo];
        #pragma unroll
        for (int xo = 0; xo < XPT; ++xo) acc[KH - 1][xo] = 0.0f;
    }
}

extern "C" void kernel_launch(void* const* d_in, const int* in_sizes, int n_in,
                              void* d_out, int out_size, void* d_ws, size_t ws_size,
                              hipStream_t stream) {
    const float* in  = (const float*)d_in[0];
    const float* ker = (const float*)d_in[1];
    float*       out = (float*)d_out;

    crossconv_kernel<<<GRID, 1024, 0, stream>>>(in, ker, out);
}

// Round 4
// 167.651 us; speedup vs baseline: 2.9594x; 2.0028x over previous
//
#include <hip/hip_runtime.h>

// Per-sample depthwise 7x7 cross-correlation, NHWC, SAME padding.
// inputs:  [B,H,W,C] fp32, kernels: [B,7,7,C] fp32, out: [B,H,W,C] fp32.
// out[b,y,x,c] = sum_{i,j} in[b, y+i-3, x+j-3, c] * ker[b,i,j,c]  (zero pad)
//
// Weights live in LDS (not registers): 64-VGPR tier fits with zero spills.
// LDS layout lds_w[c*52 + f], f = i*7+j. Stride 52 floats = 208 B = 13*16 B:
// ds_read_b128 aligned, quad-bank = c*13 mod 8 (13 odd -> bijection) -> conflict-free.

#define BB 32
#define HH 128
#define WW 128
#define CC 128
#define KH 7
#define KW 7

#define XPT 4                        // x outputs per thread
#define NTAP (XPT + KW - 1)          // 10 input columns per row per thread
#define XG 8                         // x-groups per block (1024 threads / 128 c)
#define SLABW (XG * XPT)             // 32 output columns per block
#define NXS (WW / SLABW)             // 4 x-slabs
#define YSPLIT 4
#define YROWS (HH / YSPLIT)          // 32 output rows per block
#define GRID (BB * NXS * YSPLIT)     // 512 blocks = 2 per CU
#define WSTRIDE 52                   // padded per-c weight stride (floats)

__global__ __launch_bounds__(1024) void crossconv_kernel(
    const float* __restrict__ in,
    const float* __restrict__ ker,
    float* __restrict__ out)
{
    __shared__ float lds_w[CC * WSTRIDE];   // 26624 B

    const int tid = threadIdx.x;
    const int c  = tid & (CC - 1);   // lanes contiguous in c -> coalesced
    const int xg = tid >> 7;         // 0..7, wave-uniform (wave = 64 lanes)

    // Bijective XCD swizzle (GRID=512, 64 blocks/XCD): each XCD gets 4 whole
    // samples (16 blocks each: 4 x-slabs x 4 y-quarters) -> halo reuse in L2.
    const int bid = blockIdx.x;
    const int swz = (bid & 7) * (GRID / 8) + (bid >> 3);
    const int b  = swz >> 4;         // 16 blocks per sample
    const int xs = (swz >> 2) & 3;
    const int yh = swz & 3;
    const int x0 = xs * SLABW + xg * XPT;  // first output column for this thread
    const int y0 = yh * YROWS;

    // Stage this sample's weights into LDS, transposed to [c][f].
    {
        const float* kb = ker + ((size_t)b * KH * KW) * CC + c;
        for (int f = xg; f < KH * KW; f += XG)
            lds_w[c * WSTRIDE + f] = kb[f * CC];
    }
    __syncthreads();

    const float* ib = in  + ((size_t)b * HH * WW) * CC;
    float*       ob = out + ((size_t)b * HH * WW) * CC;
    const float* wp = &lds_w[c * WSTRIDE];

    // Taps cover columns x0-3 .. x0+XPT+2; wave-uniform edge test.
    const bool interior = (x0 >= 3) && (x0 + XPT + 2 < WW);

    // Sliding accumulator ring: acc[s][xo] is partial for output row y = yi-3+s.
    float acc[KH][XPT];
    #pragma unroll
    for (int s = 0; s < KH; ++s)
        #pragma unroll
        for (int xo = 0; xo < XPT; ++xo) acc[s][xo] = 0.0f;

    const int yi0 = y0 - 3;
    const int yi1 = y0 + YROWS + 2;  // last input row feeding y0+YROWS-1

    #pragma unroll 1
    for (int yi = yi0; yi <= yi1; ++yi) {
        // Load this row's taps (issued first; can overlap prior row's FMAs).
        float t[NTAP];
        if (yi >= 0 && yi < HH) {
            const float* row = ib + (size_t)yi * WW * CC + c;
            if (interior) {
                #pragma unroll
                for (int j = 0; j < NTAP; ++j)
                    t[j] = row[(x0 - 3 + j) * CC];
            } else {
                #pragma unroll
                for (int j = 0; j < NTAP; ++j) {
                    const int xx = x0 - 3 + j;
                    t[j] = (xx >= 0 && xx < WW) ? row[xx * CC] : 0.0f;
                }
            }
        } else {
            #pragma unroll
            for (int j = 0; j < NTAP; ++j) t[j] = 0.0f;
        }

        // Block LICM from hoisting the per-row LDS weight reads into registers
        // (that would recreate the 49-reg pressure and spill).
        asm volatile("" ::: "memory");

        // Input row yi feeds output y = yi-3+s with kernel row i = 6-s.
        // Stream weights from LDS as 12x b128 + 1x b32, consume immediately.
        #pragma unroll
        for (int k = 0; k < 12; ++k) {
            const float4 q = *(const float4*)(wp + k * 4);
            #pragma unroll
            for (int m = 0; m < 4; ++m) {
                const int f = k * 4 + m;
                const int i = f / KW, j = f % KW;
                const float wv = (&q.x)[m];
                #pragma unroll
                for (int xo = 0; xo < XPT; ++xo)
                    acc[6 - i][xo] = fmaf(wv, t[xo + j], acc[6 - i][xo]);
            }
        }
        {   // f = 48 -> i = 6, j = 6
            const float wv = wp[48];
            #pragma unroll
            for (int xo = 0; xo < XPT; ++xo)
                acc[0][xo] = fmaf(wv, t[xo + 6], acc[0][xo]);
        }

        const int y = yi - 3;
        if (y >= y0) {                       // upper bound guaranteed by loop end
            float* orow = ob + ((size_t)y * WW + x0) * CC + c;
            #pragma unroll
            for (int xo = 0; xo < XPT; ++xo)
                orow[xo * CC] = acc[0][xo];
        }

        // Shift ring, open fresh top slot.
        #pragma unroll
        for (int s = 0; s < KH - 1; ++s)
            #pragma unroll
            for (int xo = 0; xo < XPT; ++xo) acc[s][xo] = acc[s + 1][xo];
        #pragma unroll
        for (int xo = 0; xo < XPT; ++xo) acc[KH - 1][xo] = 0.0f;
    }
}

extern "C" void kernel_launch(void* const* d_in, const int* in_sizes, int n_in,
                              void* d_out, int out_size, void* d_ws, size_t ws_size,
                              hipStream_t stream) {
    const float* in  = (const float*)d_in[0];
    const float* ker = (const float*)d_in[1];
    float*       out = (float*)d_out;

    crossconv_kernel<<<GRID, 1024, 0, stream>>>(in, ker, out);
}